// Round 4
// baseline (856.157 us; speedup 1.0000x reference)
//
#include <hip/hip_runtime.h>

// Problem constants (from reference): z (64,128,64,64) f32, emb (256,128) f32
#define K_EMB   256
#define C_DIM   128
#define HW      4096            // 64*64
#define NPOS    262144          // 64*HW
#define Q_ELEMS 33554432        // 64*128*64*64
#define IDX_OFF Q_ELEMS         // idx chunk offset in d_out (floats)
#define LOSS_OFF (Q_ELEMS + NPOS)

// ws layout (floats): [0,256) enorm, [256] loss accumulator, [512, 512+32768) embT (c*256+k)
#define WS_ENORM 0
#define WS_ACC   256
#define WS_EMBT  512
#define WS_NEED_FULL  ((WS_EMBT + C_DIM * K_EMB) * 4)

// ---------------------------------------------------------------------------
// Kernel 0: per-code squared norms, optional emb transpose, zero loss accum.
// ---------------------------------------------------------------------------
__global__ __launch_bounds__(K_EMB) void vq_prep(const float* __restrict__ emb,
                                                 float* __restrict__ ws,
                                                 int use_embT) {
    int k = threadIdx.x;  // 256 threads, 1 block
    float s = 0.f;
    #pragma unroll 8
    for (int c = 0; c < C_DIM; ++c) {
        float e = emb[k * C_DIM + c];
        s = fmaf(e, e, s);
        if (use_embT) ws[WS_EMBT + c * K_EMB + k] = e;
    }
    ws[WS_ENORM + k] = s;
    if (k == 0) ws[WS_ACC] = 0.f;
}

// ---------------------------------------------------------------------------
// Kernel 1: main VQ. One position per lane; 256-thread blocks (4 waves) to
// escape the per-CU workgroup-slot cap seen with 64-thread blocks (Occ 25%).
//
// zr[128] residency history:
//   R1/R2: partial unroll -> runtime index -> scratch spill (+134 MB writes)
//   R3: full unroll -> compiler REMATERIALIZED zr by re-loading invariant z
//       inside the k-loop (VGPR=76, FETCH absorbed by L2/L3, VALUBusy 38%)
// Fix: opaque asm pins each zr value in a VGPR -- not rematerializable.
// k-loop is then v_fmac_f32 (VGPR x s_loaded codebook row). No LDS.
// ---------------------------------------------------------------------------
__global__ __launch_bounds__(256, 2) void vq_main(const float* __restrict__ z,
                                                  const float* __restrict__ emb,
                                                  const float* __restrict__ ws,
                                                  float* __restrict__ out,
                                                  float* __restrict__ loss_acc,
                                                  int use_embT) {
    const int pos  = blockIdx.x * 256 + threadIdx.x;   // flat (b, h, w)
    const int b    = pos >> 12;                        // / 4096
    const int hw   = pos & 4095;

    const float* zp = z + (size_t)b * (C_DIM * HW) + hw;

    // Load this lane's position vector (coalesced across lanes per c).
    float zr[C_DIM];
    #pragma unroll
    for (int c = 0; c < C_DIM; ++c) zr[c] = zp[(size_t)c * HW];

    // Pin zr in VGPRs: opaque asm defeats rematerialization / re-load.
    #pragma unroll
    for (int c = 0; c < C_DIM; ++c) asm volatile("" : "+v"(zr[c]));

    float znorm = 0.f;
    #pragma unroll
    for (int c = 0; c < C_DIM; ++c) znorm = fmaf(zr[c], zr[c], znorm);

    // Argmin over codes; d = (||z||^2 - 2 z.e) + ||e||^2 (reference formula).
    // 4 partial accumulators break the 128-long dependent FMA chain
    // (issue 256 cyc vs chain 32*4=128 cyc -> issue-bound).
    float best = 3.402823466e38f;
    int bidx = 0;
    #pragma unroll 2
    for (int k = 0; k < K_EMB; ++k) {
        const float* __restrict__ ek = emb + k * C_DIM;  // wave-uniform row
        float a0 = 0.f, a1 = 0.f, a2 = 0.f, a3 = 0.f;
        #pragma unroll
        for (int c = 0; c < C_DIM; c += 4) {
            a0 = fmaf(zr[c + 0], ek[c + 0], a0);
            a1 = fmaf(zr[c + 1], ek[c + 1], a1);
            a2 = fmaf(zr[c + 2], ek[c + 2], a2);
            a3 = fmaf(zr[c + 3], ek[c + 3], a3);
        }
        float acc = (a0 + a1) + (a2 + a3);
        float d = (znorm - 2.0f * acc) + ws[WS_ENORM + k];
        if (d < best) { best = d; bidx = k; }   // strict < = first-min tiebreak
    }

    out[IDX_OFF + pos] = (float)bidx;

    // Epilogue: quantized_ste = z + (e - z), accumulate (e - z)^2.
    // Fully unrolled (compile-time zr indices).
    float lsum = 0.f;
    float* qp = out + (size_t)b * (C_DIM * HW) + hw;
    if (use_embT) {
        const float* __restrict__ embT = ws + WS_EMBT;
        #pragma unroll
        for (int c = 0; c < C_DIM; ++c) {
            float e  = embT[c * K_EMB + bidx];
            float dq = e - zr[c];
            lsum = fmaf(dq, dq, lsum);
            qp[(size_t)c * HW] = zr[c] + dq;
        }
    } else {
        #pragma unroll
        for (int c = 0; c < C_DIM; ++c) {
            float e  = emb[bidx * C_DIM + c];
            float dq = e - zr[c];
            lsum = fmaf(dq, dq, lsum);
            qp[(size_t)c * HW] = zr[c] + dq;
        }
    }

    // Wave-level reduction, one atomic per wave.
    #pragma unroll
    for (int off = 32; off > 0; off >>= 1)
        lsum += __shfl_down(lsum, off, 64);
    if ((threadIdx.x & 63) == 0) atomicAdd(loss_acc, lsum);
}

// ---------------------------------------------------------------------------
// Kernel 2: finalize the two scalar losses.
// ---------------------------------------------------------------------------
__global__ void vq_finalize(const float* __restrict__ loss_acc,
                            float* __restrict__ out_losses) {
    float S = loss_acc[0];
    float mean = S / (float)Q_ELEMS;
    out_losses[0] = 0.25f * mean;  // commitment_loss
    out_losses[1] = mean;          // codebook_loss
}

extern "C" void kernel_launch(void* const* d_in, const int* in_sizes, int n_in,
                              void* d_out, int out_size, void* d_ws, size_t ws_size,
                              hipStream_t stream) {
    const float* z   = (const float*)d_in[0];
    const float* emb = (const float*)d_in[1];
    float* out = (float*)d_out;
    float* ws  = (float*)d_ws;

    int use_embT = (ws_size >= (size_t)WS_NEED_FULL) ? 1 : 0;

    vq_prep<<<1, K_EMB, 0, stream>>>(emb, ws, use_embT);
    vq_main<<<NPOS / 256, 256, 0, stream>>>(z, emb, ws, out, ws + WS_ACC, use_embT);
    vq_finalize<<<1, 1, 0, stream>>>(ws + WS_ACC, out + LOSS_OFF);
}

// Round 5
// 515.402 us; speedup vs baseline: 1.6611x; 1.6611x over previous
//
#include <hip/hip_runtime.h>

// Problem constants (from reference): z (64,128,64,64) f32, emb (256,128) f32
#define K_EMB   256
#define C_DIM   128
#define HW      4096            // 64*64
#define NPOS    262144          // 64*HW
#define Q_ELEMS 33554432        // 64*128*64*64
#define IDX_OFF Q_ELEMS         // idx chunk offset in d_out (floats)
#define LOSS_OFF (Q_ELEMS + NPOS)

#define TK 32                   // codes per k-chunk (accumulators per lane)

// ws layout (floats): [0,256) enorm, [256] loss accumulator, [512, 512+32768) embT (c*256+k)
#define WS_ENORM 0
#define WS_ACC   256
#define WS_EMBT  512
#define WS_NEED_FULL  ((WS_EMBT + C_DIM * K_EMB) * 4)

// ---------------------------------------------------------------------------
// Kernel 0: per-code squared norms, emb transpose (c-major), zero loss accum.
// ---------------------------------------------------------------------------
__global__ __launch_bounds__(K_EMB) void vq_prep(const float* __restrict__ emb,
                                                 float* __restrict__ ws,
                                                 int use_embT) {
    int k = threadIdx.x;  // 256 threads, 1 block
    float s = 0.f;
    #pragma unroll 8
    for (int c = 0; c < C_DIM; ++c) {
        float e = emb[k * C_DIM + c];
        s = fmaf(e, e, s);
        if (use_embT) ws[WS_EMBT + c * K_EMB + k] = e;
    }
    ws[WS_ENORM + k] = s;
    if (k == 0) ws[WS_ACC] = 0.f;
}

// ---------------------------------------------------------------------------
// Kernel 1: register-blocked VALU GEMM + argmin.
//
// R1-R4 history: the 1-position-per-lane / zr[128]-resident design lost to
// the register allocator three different ways (scratch spill, remat re-load,
// AGPR parking) -- VALUBusy never exceeded 40%. This version inverts the
// blocking: each lane streams c and holds TK=32 code-score accumulators.
//   per c-step: 1 vector z load + 32 wave-uniform embT values (contiguous
//   -> s_load_dwordx16 on the scalar pipe) + 32 v_fmac_f32 (VGPR x SGPR).
// Register pressure ~70 VGPRs -> real occupancy; z re-streamed K/TK=8 times
// from L2/L3 (134 MB << 256 MB L3), overlapped with the 109 us VALU floor.
//
// Numerics: dot accumulated serially over ascending c, d = (znorm - 2*acc)
// + enorm[k], strict < ascending-k tiebreak -- bit-identical to the R1
// kernel that passed with absmax 0.
// ---------------------------------------------------------------------------
template <int UT>
__global__ __launch_bounds__(256, 4) void vq_main(const float* __restrict__ z,
                                                  const float* __restrict__ emb,
                                                  const float* __restrict__ ws,
                                                  float* __restrict__ out,
                                                  float* __restrict__ loss_acc) {
    const int pos = blockIdx.x * 256 + threadIdx.x;   // flat (b, h, w)
    const int b   = pos >> 12;                        // / 4096
    const int hw  = pos & 4095;

    const float* __restrict__ zp    = z + (size_t)b * (C_DIM * HW) + hw;
    const float* __restrict__ embT  = ws + WS_EMBT;
    const float* __restrict__ enorm = ws + WS_ENORM;

    // znorm prepass (serial ascending c -- same order as R1; warms L1/L2).
    float znorm = 0.f;
    #pragma unroll 8
    for (int c = 0; c < C_DIM; ++c) {
        float zc = zp[(size_t)c * HW];
        znorm = fmaf(zc, zc, znorm);
    }

    float best = 3.402823466e38f;
    int bidx = 0;

    for (int kc = 0; kc < K_EMB; kc += TK) {
        float acc[TK];
        #pragma unroll
        for (int j = 0; j < TK; ++j) acc[j] = 0.f;

        #pragma unroll 2
        for (int c = 0; c < C_DIM; ++c) {
            float zc = zp[(size_t)c * HW];            // per-lane vector load
            if (UT) {
                const float* ep = embT + c * K_EMB + kc;  // wave-uniform, contiguous
                #pragma unroll
                for (int j = 0; j < TK; ++j)
                    acc[j] = fmaf(zc, ep[j], acc[j]);
            } else {
                #pragma unroll
                for (int j = 0; j < TK; ++j)
                    acc[j] = fmaf(zc, emb[(kc + j) * C_DIM + c], acc[j]);
            }
        }

        #pragma unroll
        for (int j = 0; j < TK; ++j) {
            float d = (znorm - 2.0f * acc[j]) + enorm[kc + j];
            if (d < best) { best = d; bidx = kc + j; }  // strict < = first-min
        }
    }

    out[IDX_OFF + pos] = (float)bidx;

    // Epilogue: quantized_ste = z + (e - z), accumulate (e - z)^2.
    // z re-read is L2/L3-hot by now.
    float lsum = 0.f;
    float* qp = out + (size_t)b * (C_DIM * HW) + hw;
    #pragma unroll 4
    for (int c = 0; c < C_DIM; ++c) {
        float zc = zp[(size_t)c * HW];
        float e  = UT ? embT[c * K_EMB + bidx] : emb[bidx * C_DIM + c];
        float dq = e - zc;
        lsum = fmaf(dq, dq, lsum);
        qp[(size_t)c * HW] = zc + dq;
    }

    // Wave-level reduction, one atomic per wave.
    #pragma unroll
    for (int off = 32; off > 0; off >>= 1)
        lsum += __shfl_down(lsum, off, 64);
    if ((threadIdx.x & 63) == 0) atomicAdd(loss_acc, lsum);
}

// ---------------------------------------------------------------------------
// Kernel 2: finalize the two scalar losses.
// ---------------------------------------------------------------------------
__global__ void vq_finalize(const float* __restrict__ loss_acc,
                            float* __restrict__ out_losses) {
    float S = loss_acc[0];
    float mean = S / (float)Q_ELEMS;
    out_losses[0] = 0.25f * mean;  // commitment_loss
    out_losses[1] = mean;          // codebook_loss
}

extern "C" void kernel_launch(void* const* d_in, const int* in_sizes, int n_in,
                              void* d_out, int out_size, void* d_ws, size_t ws_size,
                              hipStream_t stream) {
    const float* z   = (const float*)d_in[0];
    const float* emb = (const float*)d_in[1];
    float* out = (float*)d_out;
    float* ws  = (float*)d_ws;

    int use_embT = (ws_size >= (size_t)WS_NEED_FULL) ? 1 : 0;

    vq_prep<<<1, K_EMB, 0, stream>>>(emb, ws, use_embT);
    if (use_embT)
        vq_main<1><<<NPOS / 256, 256, 0, stream>>>(z, emb, ws, out, ws + WS_ACC);
    else
        vq_main<0><<<NPOS / 256, 256, 0, stream>>>(z, emb, ws, out, ws + WS_ACC);
    vq_finalize<<<1, 1, 0, stream>>>(ws + WS_ACC, out + LOSS_OFF);
}